// Round 2
// baseline (1473.545 us; speedup 1.0000x reference)
//
#include <hip/hip_runtime.h>

// BioRNN: T=1000, B=4096, H=50, IN=8, OUT=6, fp32.
//   r   = relu(h)
//   y_t = r @ W_out^T + b_out          (r from PRE-update h)
//   h  += DT * (-h + x @ W_in^T + r @ W_rec^T + bias)
//
// v2 restructure: TWO batch elements per lane, same weight row.
// Round-1 evidence: VGPR_Count=48 with ~70 live floats/lane => weights were
// parked in AGPRs under the launch_bounds(256,4) 128-reg budget, costing
// ~60 v_accvgpr_read copies per wave-step (VALUBusy 69% = 2.3x the useful
// FMA issue). Fix: each wave owns 2 batch elements; each lane computes two
// independent dot products against ONE register-resident weight row
// (weight cost amortized 2x), and __launch_bounds__(256,2) gives a 256-reg
// budget so everything lives in arch VGPRs (~100 regs, no AGPR round-trips).
// Grid: 512 blocks x 4 waves = 2048 waves = 2 waves/SIMD. Issue-bound
// kernel => halving the per-FMA instruction overhead beats the occupancy
// loss (kernel was only 31% idle).
//
// r-exchange stays wave-internal: 2x ds_write_b32 + lgkmcnt(0) + 26
// broadcast ds_read_b128, no __syncthreads. Single-buffer LDS is race-free
// (step t+1's writes are register-RAW-dependent on all of step t's reads).
// Per-lane per-batch-element accumulation order is BIT-IDENTICAL to the
// previous passing kernels: acc = bias -> k=0..51 in float4 order ->
// x i=0..7 -> h += DT*(acc - h).

#define T_STEPS 1000
#define BATCH   4096
#define INSZ    8
#define H       50
#define OUTSZ   6
#define DT      0.1f
#define ROWS    56         // 50 hidden + 6 output projections
#define KP      52         // padded dot length (13 * float4; k=50,51 weight=0)
#define WPB     4          // waves per block
#define BPW     2          // batch elements per wave

__global__ __launch_bounds__(256, 2)
void biornn_kernel(const float* __restrict__ xg,   // (T, B, INSZ)
                   const float* __restrict__ Wi,   // (H, INSZ)
                   const float* __restrict__ Wr,   // (H, H)
                   const float* __restrict__ bs,   // (H)
                   const float* __restrict__ Wo,   // (OUTSZ, H)
                   const float* __restrict__ bo,   // (OUTSZ)
                   float* __restrict__ out)        // (T, B, OUTSZ)
{
    // one row of 64 floats per batch element; writes stride-1 (conflict-
    // free), reads are same-address broadcast (conflict-free).
    __shared__ __align__(16) float r_lds[WPB * BPW][64];

    const int tid  = threadIdx.x;
    const int w    = tid >> 6;            // wave in block
    const int lane = tid & 63;            // row index this lane owns
    const int b0   = blockIdx.x * (WPB * BPW) + w * BPW;  // b1 = b0 + 1

    const bool hrow = (lane < H);
    const bool yrow = (lane >= H) && (lane < ROWS);

    // ---- loop-invariant weights into registers (one row per lane) ----
    float wr[KP], wi[INSZ];
    float bias = 0.f;
#pragma unroll
    for (int k = 0; k < KP; ++k) wr[k] = 0.f;
#pragma unroll
    for (int i = 0; i < INSZ; ++i) wi[i] = 0.f;

    if (hrow) {
#pragma unroll
        for (int k = 0; k < H; ++k) wr[k] = Wr[lane * H + k];
#pragma unroll
        for (int i = 0; i < INSZ; ++i) wi[i] = Wi[lane * INSZ + i];
        bias = bs[lane];
    } else if (yrow) {
        const int o = lane - H;
#pragma unroll
        for (int k = 0; k < H; ++k) wr[k] = Wo[o * H + k];
        bias = bo[o];
    }
    // lanes 56..63: all-zero weights, bias 0 -> h stays 0, never stored.

    // ---- per-lane state: two independent batch elements ----
    float h0 = 0.f, h1 = 0.f;

    // x[t] for both batch elements: b0,b1 consecutive -> contiguous 64B.
    // Wave-uniform addresses (1 cache line), prefetched one step ahead.
    const float* xp = xg + (size_t)b0 * INSZ;
    float xv0[INSZ], xv1[INSZ];
#pragma unroll
    for (int i = 0; i < INSZ; i += 4) {
        float4 a4 = *(const float4*)(xp + i);
        float4 b4 = *(const float4*)(xp + INSZ + i);
        xv0[i] = a4.x; xv0[i + 1] = a4.y; xv0[i + 2] = a4.z; xv0[i + 3] = a4.w;
        xv1[i] = b4.x; xv1[i + 1] = b4.y; xv1[i + 2] = b4.z; xv1[i + 3] = b4.w;
    }
    xp += (size_t)BATCH * INSZ;

    // y-row output pointer for b0 (b1 is +OUTSZ); dummy for other lanes.
    float* op = out + (size_t)b0 * OUTSZ + (yrow ? (lane - H) : 0);

    for (int t = 0; t < T_STEPS; ++t) {
        // publish r = relu(h) for both batch elements. Lanes 50..55 publish
        // finite garbage into slots 50..55; only slots 50,51 are ever read
        // and their weights are 0 (fma(g, 0, acc) == acc exactly, g finite).
        const float r0 = fmaxf(h0, 0.f);
        const float r1 = fmaxf(h1, 0.f);
        r_lds[BPW * w + 0][lane] = r0;
        r_lds[BPW * w + 1][lane] = r1;
        // wave-internal visibility: wait own wave's ds_writes.
        asm volatile("s_waitcnt lgkmcnt(0)" ::: "memory");

        float acc0 = bias, acc1 = bias;
#pragma unroll
        for (int kc = 0; kc < KP / 4; ++kc) {
            const float4 ra = *(const float4*)&r_lds[BPW * w + 0][4 * kc];
            const float4 rb = *(const float4*)&r_lds[BPW * w + 1][4 * kc];
            acc0 = fmaf(ra.x, wr[4 * kc + 0], acc0);
            acc1 = fmaf(rb.x, wr[4 * kc + 0], acc1);
            acc0 = fmaf(ra.y, wr[4 * kc + 1], acc0);
            acc1 = fmaf(rb.y, wr[4 * kc + 1], acc1);
            acc0 = fmaf(ra.z, wr[4 * kc + 2], acc0);
            acc1 = fmaf(rb.z, wr[4 * kc + 2], acc1);
            acc0 = fmaf(ra.w, wr[4 * kc + 3], acc0);
            acc1 = fmaf(rb.w, wr[4 * kc + 3], acc1);
        }
#pragma unroll
        for (int i = 0; i < INSZ; ++i) {
            acc0 = fmaf(xv0[i], wi[i], acc0);
            acc1 = fmaf(xv1[i], wi[i], acc1);
        }

        // prefetch x[t+1] (consumed next iteration; vmcnt wait lands there)
        if (t + 1 < T_STEPS) {
#pragma unroll
            for (int i = 0; i < INSZ; i += 4) {
                float4 a4 = *(const float4*)(xp + i);
                float4 b4 = *(const float4*)(xp + INSZ + i);
                xv0[i] = a4.x; xv0[i+1] = a4.y; xv0[i+2] = a4.z; xv0[i+3] = a4.w;
                xv1[i] = b4.x; xv1[i+1] = b4.y; xv1[i+2] = b4.z; xv1[i+3] = b4.w;
            }
            xp += (size_t)BATCH * INSZ;
        }

        // h <- h + DT*(acc - h). Harmless on y/dummy rows (h unused there).
        h0 += DT * (acc0 - h0);
        h1 += DT * (acc1 - h1);

        // output rows: y_t = acc (b_out folded into bias init)
        if (yrow) {
            op[0]     = acc0;
            op[OUTSZ] = acc1;
            op += (size_t)BATCH * OUTSZ;
        }
    }
}

extern "C" void kernel_launch(void* const* d_in, const int* in_sizes, int n_in,
                              void* d_out, int out_size, void* d_ws, size_t ws_size,
                              hipStream_t stream)
{
    const float* xg = (const float*)d_in[0];  // input_seq (1000,4096,8)
    const float* Wi = (const float*)d_in[1];  // W_in (50,8)
    const float* Wr = (const float*)d_in[2];  // W_rec (50,50)
    const float* bs = (const float*)d_in[3];  // bias (50)
    const float* Wo = (const float*)d_in[4];  // W_out_w (6,50)
    const float* bo = (const float*)d_in[5];  // W_out_b (6)
    float* outp = (float*)d_out;              // (1000,4096,6)

    dim3 grid(BATCH / (WPB * BPW));   // 512 blocks
    dim3 block(256);                  // 4 waves, each owning 2 batch elems
    hipLaunchKernelGGL(biornn_kernel, grid, block, 0, stream,
                       xg, Wi, Wr, bs, Wo, bo, outp);
}

// Round 3
// 1132.109 us; speedup vs baseline: 1.3016x; 1.3016x over previous
//
#include <hip/hip_runtime.h>

// BioRNN: T=1000, B=4096, H=50, IN=8, OUT=6, fp32.
//   r   = relu(h)
//   y_t = r @ W_out^T + b_out          (r from PRE-update h)
//   h  += DT * (-h + x @ W_in^T + r @ W_rec^T + bias)
//
// v3: r-distribution via v_readlane -> SGPR, ZERO LDS in the loop.
// Evidence from rounds 0-2: every LDS-based variant shows VALU-busy ~2.3-2.6x
// the useful instruction stream (AGPR/scratch parking of oversized per-lane
// arrays: VGPR_Count 92/48/84 always < live values), and the LDS round-trip
// forces waits. Here: one wave per batch element, one row per lane
// (lane 0..49 hidden, 50..55 output, 56..63 idle). Lane k's r value is read
// with __builtin_amdgcn_readlane(r, k) (compile-time k) into an SGPR and fed
// straight to v_fmac_f32 as the 1-allowed-SGPR operand. The loop body is a
// pure VALU stream: 1 relu + 50x(readlane+fmac) + 8 fmac + h-update.
// No LDS, no barriers, no lgkmcnt waits -> nothing to stall on; 4 waves/SIMD
// (grid 1024x256, launch_bounds(256,4)) cover issue latency.
// Per-lane arrays shrink to wr[50]+wi[8]+xv[8] (~80 regs incl. state) --
// inside the 128-reg budget, so no AGPR parking.
//
// Numerics: per-lane chain kept BIT-IDENTICAL to all previous passing
// kernels: acc = bias -> k=0..49 in order (the old k=50,51 pad FMAs were
// exact no-ops fma(r,0,acc)) -> x i=0..7 -> h += DT*(acc - h).

#define T_STEPS 1000
#define BATCH   4096
#define INSZ    8
#define H       50
#define OUTSZ   6
#define DT      0.1f
#define ROWS    56         // 50 hidden + 6 output projections
#define WPB     4          // waves (= batch elements) per block

__global__ __launch_bounds__(256, 4)
void biornn_kernel(const float* __restrict__ xg,   // (T, B, INSZ)
                   const float* __restrict__ Wi,   // (H, INSZ)
                   const float* __restrict__ Wr,   // (H, H)
                   const float* __restrict__ bs,   // (H)
                   const float* __restrict__ Wo,   // (OUTSZ, H)
                   const float* __restrict__ bo,   // (OUTSZ)
                   float* __restrict__ out)        // (T, B, OUTSZ)
{
    const int tid  = threadIdx.x;
    const int w    = tid >> 6;            // wave in block = batch slot
    const int lane = tid & 63;            // row index this lane owns
    const int b_glob = blockIdx.x * WPB + w;

    const bool hrow = (lane < H);
    const bool yrow = (lane >= H) && (lane < ROWS);

    // ---- loop-invariant weights into registers (one row per lane) ----
    float wr[H], wi[INSZ];
    float bias = 0.f;
#pragma unroll
    for (int k = 0; k < H; ++k) wr[k] = 0.f;
#pragma unroll
    for (int i = 0; i < INSZ; ++i) wi[i] = 0.f;

    if (hrow) {
#pragma unroll
        for (int k = 0; k < H; ++k) wr[k] = Wr[lane * H + k];
#pragma unroll
        for (int i = 0; i < INSZ; ++i) wi[i] = Wi[lane * INSZ + i];
        bias = bs[lane];
    } else if (yrow) {
        const int o = lane - H;
#pragma unroll
        for (int k = 0; k < H; ++k) wr[k] = Wo[o * H + k];
        bias = bo[o];
    }
    // lanes 56..63: all-zero weights, bias 0 -> idle-compute, never stored.

    // ---- per-lane state ----
    float h = 0.f;

    // x[t]: wave-uniform 32B, held in regs, prefetched one step ahead
    // (vector loads -> vmcnt; the only non-VALU ops in the loop).
    const float* xp = xg + (size_t)b_glob * INSZ;
    float xv[INSZ];
#pragma unroll
    for (int i = 0; i < INSZ; i += 4) {
        float4 t4 = *(const float4*)(xp + i);
        xv[i] = t4.x; xv[i + 1] = t4.y; xv[i + 2] = t4.z; xv[i + 3] = t4.w;
    }
    xp += (size_t)BATCH * INSZ;

    float* op = out + (size_t)b_glob * OUTSZ + (yrow ? (lane - H) : 0);

    for (int t = 0; t < T_STEPS; ++t) {
        // r = relu(h) in every lane; lane k holds r_k for k < 50.
        const float r = fmaxf(h, 0.f);

        float acc = bias;
#pragma unroll
        for (int k = 0; k < H; ++k) {
            // broadcast r_k from lane k to an SGPR (compile-time lane index);
            // consumed as the scalar operand of v_fmac_f32.
            const float rk = __int_as_float(
                __builtin_amdgcn_readlane(__float_as_int(r), k));
            acc = fmaf(rk, wr[k], acc);
        }
#pragma unroll
        for (int i = 0; i < INSZ; ++i)
            acc = fmaf(xv[i], wi[i], acc);

        // prefetch x[t+1] (consumed next iteration; vmcnt wait lands there)
        if (t + 1 < T_STEPS) {
#pragma unroll
            for (int i = 0; i < INSZ; i += 4) {
                float4 t4 = *(const float4*)(xp + i);
                xv[i] = t4.x; xv[i + 1] = t4.y; xv[i + 2] = t4.z; xv[i + 3] = t4.w;
            }
            xp += (size_t)BATCH * INSZ;
        }

        // h <- h + DT*(acc - h). Harmless on y/idle rows (h unused there).
        h += DT * (acc - h);

        // output rows: y_t = acc (b_out folded into bias init)
        if (yrow) {
            *op = acc;
            op += (size_t)BATCH * OUTSZ;
        }
    }
}

extern "C" void kernel_launch(void* const* d_in, const int* in_sizes, int n_in,
                              void* d_out, int out_size, void* d_ws, size_t ws_size,
                              hipStream_t stream)
{
    const float* xg = (const float*)d_in[0];  // input_seq (1000,4096,8)
    const float* Wi = (const float*)d_in[1];  // W_in (50,8)
    const float* Wr = (const float*)d_in[2];  // W_rec (50,50)
    const float* bs = (const float*)d_in[3];  // bias (50)
    const float* Wo = (const float*)d_in[4];  // W_out_w (6,50)
    const float* bo = (const float*)d_in[5];  // W_out_b (6)
    float* outp = (float*)d_out;              // (1000,4096,6)

    dim3 grid(BATCH / WPB);   // 1024 blocks
    dim3 block(256);          // 4 independent waves per block
    hipLaunchKernelGGL(biornn_kernel, grid, block, 0, stream,
                       xg, Wi, Wr, bs, Wo, bo, outp);
}

// Round 4
// 887.242 us; speedup vs baseline: 1.6608x; 1.2760x over previous
//
#include <hip/hip_runtime.h>

// BioRNN: T=1000, B=4096, H=50, IN=8, OUT=6, fp32.
//   r   = relu(h)
//   y_t = r @ W_out^T + b_out          (r from PRE-update h)
//   h  += DT * (-h + x @ W_in^T + r @ W_rec^T + bias)
//
// v4 = round-1 structure (1 wave per batch element, 1 row per lane,
// wave-internal LDS broadcast for r, no barriers) with the register
// pathology fixed:
//  * Rounds 1/3 under __launch_bounds__(256,4) (128-reg cap): allocator
//    parked the weight array in AGPRs (VGPR_Count 48/40 vs ~75 live) ->
//    ~40-60 v_accvgpr_read copies per wave-step = 2.3x VALU inflation.
//  * Round 2 under (256,2) (256-reg budget): VGPR_Count=84 ~= live count,
//    no parking. Its regression was the 2-wave/SIMD grid, not registers.
//  Fix: keep the 4096-wave grid (4 waves/SIMD physically resident as long
//  as actual VGPR_Count <= 128) but declare (256,2) so the allocator has
//  headroom and doesn't spill to AGPRs. Weights live in ext_vector_type
//  registers (compile-time indices only) to keep them SROA/regalloc-clean.
//
// r-exchange: lane writes r=relu(h) to its slot, s_waitcnt lgkmcnt(0)
// (wave-internal, in-order LDS), then 13 broadcast ds_read_b128. Single
// buffer is race-free: step t+1's write is register-RAW-dependent on every
// FMA of step t, which depends on all 13 reads of step t.
//
// Numerics BIT-IDENTICAL to all passing rounds: acc = bias -> k=0..51
// ascending (k=50,51 weights are exactly 0 -> fma no-ops) -> x i=0..7 ->
// h += DT*(acc - h).

#define T_STEPS 1000
#define BATCH   4096
#define INSZ    8
#define H       50
#define OUTSZ   6
#define DT      0.1f
#define ROWS    56         // 50 hidden + 6 output projections
#define WPB     4          // waves (= batch elements) per block

typedef float f32x16 __attribute__((ext_vector_type(16)));
typedef float f32x8  __attribute__((ext_vector_type(8)));
typedef float f32x4  __attribute__((ext_vector_type(4)));

// weight element k (0..51) from the four vector registers; k is always a
// compile-time constant after unrolling -> folds to a single vreg access.
#define WK(k) ((k) < 16 ? wA[(k)] : (k) < 32 ? wB[(k) - 16] \
              : (k) < 48 ? wC[(k) - 32] : wD[(k) - 48])

__global__ __launch_bounds__(256, 2)
void biornn_kernel(const float* __restrict__ xg,   // (T, B, INSZ)
                   const float* __restrict__ Wi,   // (H, INSZ)
                   const float* __restrict__ Wr,   // (H, H)
                   const float* __restrict__ bs,   // (H)
                   const float* __restrict__ Wo,   // (OUTSZ, H)
                   const float* __restrict__ bo,   // (OUTSZ)
                   float* __restrict__ out)        // (T, B, OUTSZ)
{
    // per-wave r buffer. Writes stride-1 (conflict-free), reads broadcast.
    __shared__ __align__(16) float r_lds[WPB][64];

    const int tid  = threadIdx.x;
    const int w    = tid >> 6;            // wave in block = batch slot
    const int lane = tid & 63;            // row index this lane owns
    const int b_glob = blockIdx.x * WPB + w;

    const bool hrow = (lane < H);
    const bool yrow = (lane >= H) && (lane < ROWS);

    // ---- loop-invariant weights in vector registers (one row per lane) --
    f32x16 wA = 0.f, wB = 0.f, wC = 0.f;
    f32x4  wD = 0.f;                       // k=48,49 real; k=50,51 zero pad
    f32x8  wiv = 0.f;
    float  bias = 0.f;

    if (lane < ROWS) {
        const float* wrow = hrow ? (Wr + lane * H) : (Wo + (lane - H) * H);
#pragma unroll
        for (int k = 0; k < 16; ++k) wA[k] = wrow[k];
#pragma unroll
        for (int k = 0; k < 16; ++k) wB[k] = wrow[16 + k];
#pragma unroll
        for (int k = 0; k < 16; ++k) wC[k] = wrow[32 + k];
        wD[0] = wrow[48];
        wD[1] = wrow[49];
        bias  = hrow ? bs[lane] : bo[lane - H];
    }
    if (hrow) {
#pragma unroll
        for (int i = 0; i < INSZ; ++i) wiv[i] = Wi[lane * INSZ + i];
    }
    // lanes 56..63: all-zero weights, bias 0 -> idle-compute, never stored.

    // ---- per-lane state ----
    float h = 0.f;

    // x[t]: wave-uniform 32B in two float4 regs, prefetched one step ahead.
    const float* xp = xg + (size_t)b_glob * INSZ;
    f32x4 xa = *(const f32x4*)(xp);
    f32x4 xb = *(const f32x4*)(xp + 4);
    xp += (size_t)BATCH * INSZ;

    float* op = out + (size_t)b_glob * OUTSZ + (yrow ? (lane - H) : 0);

    for (int t = 0; t < T_STEPS; ++t) {
        // publish r = relu(h). Slots 50..63 hold finite garbage; only
        // slots 50,51 are read and their weights are exactly 0
        // (fma(g, 0, acc) == acc, g finite).
        const float r = fmaxf(h, 0.f);
        r_lds[w][lane] = r;
        // wave-internal visibility: LDS ops of this wave are in-order.
        asm volatile("s_waitcnt lgkmcnt(0)" ::: "memory");

        float acc = bias;
#pragma unroll
        for (int kc = 0; kc < 13; ++kc) {
            const f32x4 rv = *(const f32x4*)&r_lds[w][4 * kc];
            acc = fmaf(rv[0], WK(4 * kc + 0), acc);
            acc = fmaf(rv[1], WK(4 * kc + 1), acc);
            acc = fmaf(rv[2], WK(4 * kc + 2), acc);
            acc = fmaf(rv[3], WK(4 * kc + 3), acc);
        }
#pragma unroll
        for (int i = 0; i < 4; ++i) acc = fmaf(xa[i], wiv[i], acc);
#pragma unroll
        for (int i = 0; i < 4; ++i) acc = fmaf(xb[i], wiv[4 + i], acc);

        // prefetch x[t+1] (consumed next iteration; vmcnt wait lands there)
        if (t + 1 < T_STEPS) {
            xa = *(const f32x4*)(xp);
            xb = *(const f32x4*)(xp + 4);
            xp += (size_t)BATCH * INSZ;
        }

        // h <- h + DT*(acc - h). Harmless on y/idle rows (h unused there).
        h += DT * (acc - h);

        // output rows: y_t = acc (b_out folded into bias init)
        if (yrow) {
            *op = acc;
            op += (size_t)BATCH * OUTSZ;
        }
    }
}

extern "C" void kernel_launch(void* const* d_in, const int* in_sizes, int n_in,
                              void* d_out, int out_size, void* d_ws, size_t ws_size,
                              hipStream_t stream)
{
    const float* xg = (const float*)d_in[0];  // input_seq (1000,4096,8)
    const float* Wi = (const float*)d_in[1];  // W_in (50,8)
    const float* Wr = (const float*)d_in[2];  // W_rec (50,50)
    const float* bs = (const float*)d_in[3];  // bias (50)
    const float* Wo = (const float*)d_in[4];  // W_out_w (6,50)
    const float* bo = (const float*)d_in[5];  // W_out_b (6)
    float* outp = (float*)d_out;              // (1000,4096,6)

    dim3 grid(BATCH / WPB);   // 1024 blocks -> 4096 waves -> 4/SIMD if
    dim3 block(256);          // VGPR_Count <= 128 (that's the bet)
    hipLaunchKernelGGL(biornn_kernel, grid, block, 0, stream,
                       xg, Wi, Wr, bs, Wo, bo, outp);
}

// Round 5
// 837.666 us; speedup vs baseline: 1.7591x; 1.0592x over previous
//
#include <hip/hip_runtime.h>

// BioRNN: T=1000, B=4096, H=50, IN=8, OUT=6, fp32.
//   r   = relu(h)
//   y_t = r @ W_out^T + b_out          (r from PRE-update h)
//   h  += DT * (-h + x @ W_in^T + r @ W_rec^T + bias)
//
// v5 = v4 with ONE change: pin occupancy with amdgpu_waves_per_eu(4,4).
// Cross-round evidence (VGPR_Count 92/48/84/40/44, always << ~95 live
// values; VALU-busy ~2.3x the useful stream): the backend's occupancy
// heuristic targets 8 waves/EU (64-reg budget) regardless of
// __launch_bounds__ min-waves, and "hits" it by parking loop-invariant
// weights in AGPRs -- on gfx950's UNIFIED register file that buys no
// occupancy (VGPR+AGPR is what counts; we sit at 4 waves/SIMD anyway)
// and costs ~60 v_accvgpr_read copies per wave-step. Pinning waves/EU to
// exactly 4 sets the allocator budget to 512/4 = 128 regs, which the ~95
// live values fit -- no parking, no copies.
//
// Everything else identical to v4 (740/780-us family, best structure so
// far): 1 wave per batch element, 1 row per lane (lane 0..49 hidden,
// 50..55 output, 56..63 idle), r exchanged wave-internally via LDS
// (ds_write_b32 + lgkmcnt(0) + 13 broadcast ds_read_b128, NO barriers),
// x[t+1] prefetched into regs. Single-buffer LDS is race-free: step t+1's
// write is register-RAW-dependent on every FMA of step t, which depends
// on all 13 reads of step t.
//
// Numerics BIT-IDENTICAL to all passing rounds: acc = bias -> k=0..51
// ascending (k=50,51 weights exactly 0 -> fma no-ops) -> x i=0..7 ->
// h += DT*(acc - h).

#define T_STEPS 1000
#define BATCH   4096
#define INSZ    8
#define H       50
#define OUTSZ   6
#define DT      0.1f
#define ROWS    56         // 50 hidden + 6 output projections
#define WPB     4          // waves (= batch elements) per block

typedef float f32x16 __attribute__((ext_vector_type(16)));
typedef float f32x8  __attribute__((ext_vector_type(8)));
typedef float f32x4  __attribute__((ext_vector_type(4)));

// weight element k (0..51) from the four vector registers; k is always a
// compile-time constant after unrolling -> folds to a single vreg access.
#define WK(k) ((k) < 16 ? wA[(k)] : (k) < 32 ? wB[(k) - 16] \
              : (k) < 48 ? wC[(k) - 32] : wD[(k) - 48])

__global__ __launch_bounds__(256)
__attribute__((amdgpu_waves_per_eu(4, 4)))
void biornn_kernel(const float* __restrict__ xg,   // (T, B, INSZ)
                   const float* __restrict__ Wi,   // (H, INSZ)
                   const float* __restrict__ Wr,   // (H, H)
                   const float* __restrict__ bs,   // (H)
                   const float* __restrict__ Wo,   // (OUTSZ, H)
                   const float* __restrict__ bo,   // (OUTSZ)
                   float* __restrict__ out)        // (T, B, OUTSZ)
{
    // per-wave r buffer. Writes stride-1 (conflict-free), reads broadcast.
    __shared__ __align__(16) float r_lds[WPB][64];

    const int tid  = threadIdx.x;
    const int w    = tid >> 6;            // wave in block = batch slot
    const int lane = tid & 63;            // row index this lane owns
    const int b_glob = blockIdx.x * WPB + w;

    const bool hrow = (lane < H);
    const bool yrow = (lane >= H) && (lane < ROWS);

    // ---- loop-invariant weights in vector registers (one row per lane) --
    f32x16 wA = 0.f, wB = 0.f, wC = 0.f;
    f32x4  wD = 0.f;                       // k=48,49 real; k=50,51 zero pad
    f32x8  wiv = 0.f;
    float  bias = 0.f;

    if (lane < ROWS) {
        const float* wrow = hrow ? (Wr + lane * H) : (Wo + (lane - H) * H);
#pragma unroll
        for (int k = 0; k < 16; ++k) wA[k] = wrow[k];
#pragma unroll
        for (int k = 0; k < 16; ++k) wB[k] = wrow[16 + k];
#pragma unroll
        for (int k = 0; k < 16; ++k) wC[k] = wrow[32 + k];
        wD[0] = wrow[48];
        wD[1] = wrow[49];
        bias  = hrow ? bs[lane] : bo[lane - H];
    }
    if (hrow) {
#pragma unroll
        for (int i = 0; i < INSZ; ++i) wiv[i] = Wi[lane * INSZ + i];
    }
    // lanes 56..63: all-zero weights, bias 0 -> idle-compute, never stored.

    // ---- per-lane state ----
    float h = 0.f;

    // x[t]: wave-uniform 32B in two float4 regs, prefetched one step ahead.
    const float* xp = xg + (size_t)b_glob * INSZ;
    f32x4 xa = *(const f32x4*)(xp);
    f32x4 xb = *(const f32x4*)(xp + 4);
    xp += (size_t)BATCH * INSZ;

    float* op = out + (size_t)b_glob * OUTSZ + (yrow ? (lane - H) : 0);

    for (int t = 0; t < T_STEPS; ++t) {
        // publish r = relu(h). Slots 50..63 hold finite garbage; only
        // slots 50,51 are read and their weights are exactly 0
        // (fma(g, 0, acc) == acc, g finite).
        const float r = fmaxf(h, 0.f);
        r_lds[w][lane] = r;
        // wave-internal visibility: LDS ops of this wave are in-order.
        asm volatile("s_waitcnt lgkmcnt(0)" ::: "memory");

        float acc = bias;
#pragma unroll
        for (int kc = 0; kc < 13; ++kc) {
            const f32x4 rv = *(const f32x4*)&r_lds[w][4 * kc];
            acc = fmaf(rv[0], WK(4 * kc + 0), acc);
            acc = fmaf(rv[1], WK(4 * kc + 1), acc);
            acc = fmaf(rv[2], WK(4 * kc + 2), acc);
            acc = fmaf(rv[3], WK(4 * kc + 3), acc);
        }
#pragma unroll
        for (int i = 0; i < 4; ++i) acc = fmaf(xa[i], wiv[i], acc);
#pragma unroll
        for (int i = 0; i < 4; ++i) acc = fmaf(xb[i], wiv[4 + i], acc);

        // prefetch x[t+1] (consumed next iteration; vmcnt wait lands there)
        if (t + 1 < T_STEPS) {
            xa = *(const f32x4*)(xp);
            xb = *(const f32x4*)(xp + 4);
            xp += (size_t)BATCH * INSZ;
        }

        // h <- h + DT*(acc - h). Harmless on y/idle rows (h unused there).
        h += DT * (acc - h);

        // output rows: y_t = acc (b_out folded into bias init)
        if (yrow) {
            *op = acc;
            op += (size_t)BATCH * OUTSZ;
        }
    }
}

extern "C" void kernel_launch(void* const* d_in, const int* in_sizes, int n_in,
                              void* d_out, int out_size, void* d_ws, size_t ws_size,
                              hipStream_t stream)
{
    const float* xg = (const float*)d_in[0];  // input_seq (1000,4096,8)
    const float* Wi = (const float*)d_in[1];  // W_in (50,8)
    const float* Wr = (const float*)d_in[2];  // W_rec (50,50)
    const float* bs = (const float*)d_in[3];  // bias (50)
    const float* Wo = (const float*)d_in[4];  // W_out_w (6,50)
    const float* bo = (const float*)d_in[5];  // W_out_b (6)
    float* outp = (float*)d_out;              // (1000,4096,6)

    dim3 grid(BATCH / WPB);   // 1024 blocks = 4096 waves = 4/SIMD
    dim3 block(256);
    hipLaunchKernelGGL(biornn_kernel, grid, block, 0, stream,
                       xg, Wi, Wr, bs, Wo, bo, outp);
}

// Round 6
// 634.597 us; speedup vs baseline: 2.3220x; 1.3200x over previous
//
#include <hip/hip_runtime.h>

// BioRNN: T=1000, B=4096, H=50, IN=8, OUT=6, fp32.
//   r   = relu(h)
//   y_t = r @ W_out^T + b_out          (r from PRE-update h)
//   h  += DT * (-h + x @ W_in^T + r @ W_rec^T + bias)
//
// v6: FULL INLINE-ASM main loop. Five rounds of counter evidence show the
// HIP register allocator never keeps the 60 loop-invariant weights in arch
// VGPRs (VGPR_Count 92/48/84/40/52 vs ~90 live), inflating VALU issue ~2.2x
// with register-file shuffle traffic. This version pins everything:
//   v0..v7    r-value ping-pong buffers (ds_read_b128 A/B)
//   v8..v15   x[t] buffer A      v16..v23  x[t] buffer B (2x unrolled loop)
//   v24:25 xp  v26:27 yp  v28 h  v29 acc  v30 lds-wr  v31 lds-rd
//   v32,v33 temps  v34:35 Wr-row ptr  v36:37 Wi-row ptr  v38 bias  v39 hmask
//   v40..v89  W row (50)          v90..v97  W_in row (8)
// Steady-state body: 68 VALU + 14 DS + 3 VMEM, counted lgkmcnt(1) waits on
// the broadcast reads, vmcnt(3) so the 2 x-prefetch loads + y-store stay in
// flight across the body. One wave per batch element, one row per lane
// (0..49 hidden, 50..55 output, 56..63 compute a harmless copy of row 0).
// No barriers: r-exchange is wave-internal (ds_write + lgkmcnt(0) +
// 13 broadcast ds_read_b128; DS ops of a wave are processed in order).
// LDS is DYNAMIC (1024 B at launch) so the base offset is known to be 0 and
// addresses are plain integers (w*256 + lane*4).
//
// Numerics BIT-IDENTICAL to all passing rounds: acc = bias -> k=0..49
// ascending (old k=50,51 pads were exact fma(r,0,acc) no-ops, skipped) ->
// x i=0..7 -> h += DT*(acc-h) as v_sub + v_fmac(DT).

#define T_STEPS 1000
#define BATCH   4096
#define INSZ    8
#define H       50
#define OUTSZ   6
#define WPB     4          // waves (= batch elements) per block

// ---- asm string building blocks ----
#define FMA(rv, wv) "v_fmac_f32 v29, v" #rv ", v" #wv "\n\t"
#define DSR_A(off)  "ds_read_b128 v[0:3], v31 offset:" #off "\n\t"
#define DSR_B(off)  "ds_read_b128 v[4:7], v31 offset:" #off "\n\t"
#define W1          "s_waitcnt lgkmcnt(1)\n\t"

// relu(h) -> publish to LDS -> wait own-wave write -> acc = bias
#define RELU_PUB \
    "v_max_f32 v33, 0, v28\n\t"            \
    "ds_write_b32 v30, v33\n\t"            \
    "s_waitcnt lgkmcnt(0)\n\t"             \
    "v_mov_b32 v29, v38\n\t"

// 13 broadcast ds_read_b128 (r[0..51]) interleaved with the 50-FMA chain.
// Ping-pong buffers, exactly one read in flight past the one being consumed.
#define RCHAIN \
    DSR_A(0)  DSR_B(16)                                   \
    W1 FMA(0,40) FMA(1,41) FMA(2,42) FMA(3,43)            \
    DSR_A(32)                                             \
    W1 FMA(4,44) FMA(5,45) FMA(6,46) FMA(7,47)            \
    DSR_B(48)                                             \
    W1 FMA(0,48) FMA(1,49) FMA(2,50) FMA(3,51)            \
    DSR_A(64)                                             \
    W1 FMA(4,52) FMA(5,53) FMA(6,54) FMA(7,55)            \
    DSR_B(80)                                             \
    W1 FMA(0,56) FMA(1,57) FMA(2,58) FMA(3,59)            \
    DSR_A(96)                                             \
    W1 FMA(4,60) FMA(5,61) FMA(6,62) FMA(7,63)            \
    DSR_B(112)                                            \
    W1 FMA(0,64) FMA(1,65) FMA(2,66) FMA(3,67)            \
    DSR_A(128)                                            \
    W1 FMA(4,68) FMA(5,69) FMA(6,70) FMA(7,71)            \
    DSR_B(144)                                            \
    W1 FMA(0,72) FMA(1,73) FMA(2,74) FMA(3,75)            \
    DSR_A(160)                                            \
    W1 FMA(4,76) FMA(5,77) FMA(6,78) FMA(7,79)            \
    DSR_B(176)                                            \
    W1 FMA(0,80) FMA(1,81) FMA(2,82) FMA(3,83)            \
    DSR_A(192)                                            \
    W1 FMA(4,84) FMA(5,85) FMA(6,86) FMA(7,87)            \
    "s_waitcnt lgkmcnt(0)\n\t"                            \
    FMA(0,88) FMA(1,89)

// y-store (exec-masked to lanes 50..55) + advance yp + h-update
#define TAIL \
    "s_and_saveexec_b64 s[62:63], %12\n\t"                \
    "global_store_dword v[26:27], v29, off\n\t"           \
    "s_mov_b64 exec, s[62:63]\n\t"                        \
    "v_add_co_u32 v26, vcc, 0x18000, v26\n\t"             \
    "v_addc_co_u32 v27, vcc, 0, v27, vcc\n\t"             \
    "v_sub_f32 v32, v29, v28\n\t"                         \
    "v_fmac_f32 v28, 0x3dcccccd, v32\n\t"

// body A: consume x in v8..v15, prefetch next into v16..v23 (inc always)
#define PRE_A \
    "v_add_co_u32 v24, vcc, 0x20000, v24\n\t"             \
    "v_addc_co_u32 v25, vcc, 0, v25, vcc\n\t"             \
    "global_load_dwordx4 v[16:19], v[24:25], off\n\t"     \
    "global_load_dwordx4 v[20:23], v[24:25], off offset:16\n\t"

// body B: consume x in v16..v23, prefetch into v8..v15
// (inc = 0 on the last iteration so the final dummy load re-reads x[999])
#define PRE_B \
    "s_cmp_lg_u32 s64, 0\n\t"                             \
    "s_cselect_b32 s65, s66, 0\n\t"                       \
    "v_add_co_u32 v24, vcc, s65, v24\n\t"                 \
    "v_addc_co_u32 v25, vcc, 0, v25, vcc\n\t"             \
    "global_load_dwordx4 v[8:11], v[24:25], off\n\t"      \
    "global_load_dwordx4 v[12:15], v[24:25], off offset:16\n\t"

#define XFMA_A \
    "s_waitcnt vmcnt(3)\n\t"                              \
    FMA(8,90) FMA(9,91) FMA(10,92) FMA(11,93)             \
    FMA(12,94) FMA(13,95) FMA(14,96) FMA(15,97)

#define XFMA_B \
    "s_waitcnt vmcnt(3)\n\t"                              \
    FMA(16,90) FMA(17,91) FMA(18,92) FMA(19,93)           \
    FMA(20,94) FMA(21,95) FMA(22,96) FMA(23,97)

__global__ __launch_bounds__(256)
void biornn_kernel(const float* __restrict__ xg,   // (T, B, INSZ)
                   const float* __restrict__ Wi,   // (H, INSZ)
                   const float* __restrict__ Wr,   // (H, H)
                   const float* __restrict__ bs,   // (H)
                   const float* __restrict__ Wo,   // (OUTSZ, H)
                   const float* __restrict__ bo,   // (OUTSZ)
                   float* __restrict__ out)        // (T, B, OUTSZ)
{
    const int tid  = threadIdx.x;
    const int lane = tid & 63;
    const int w    = tid >> 6;
    const int b_glob = blockIdx.x * WPB + w;

    const bool hrow = (lane < H);
    const bool yrow = (lane >= H) && (lane < H + OUTSZ);

    // Per-lane row pointers (all deref'd for exactly 200B / 32B -- idle and
    // y lanes get safe substitutes; idle lanes compute a copy of row 0,
    // which is bounded and never stored).
    const int li = hrow ? lane : 0;
    const int oi = yrow ? (lane - H) : 0;
    const float* wrow = hrow ? (Wr + lane * H) : (yrow ? (Wo + oi * H) : Wr);
    const float* wip  = hrow ? (Wi + lane * INSZ) : Wi;
    const float* xp0  = xg + (size_t)b_glob * INSZ;
    float*       yp0  = out + (size_t)b_glob * OUTSZ + oi;
    const float  bias = hrow ? bs[li] : (yrow ? bo[oi] : 0.f);
    const float  hmask = hrow ? 1.f : 0.f;     // zeroes W_in for non-h rows
    const unsigned ldswr = (unsigned)(w * 256 + lane * 4);
    const unsigned ldsrd = (unsigned)(w * 256);
    const unsigned long long ymask = __ballot(yrow ? 1 : 0);

    const unsigned wrow_lo = (unsigned)(size_t)wrow;
    const unsigned wrow_hi = (unsigned)((size_t)wrow >> 32);
    const unsigned wip_lo  = (unsigned)(size_t)wip;
    const unsigned wip_hi  = (unsigned)((size_t)wip  >> 32);
    const unsigned xp_lo   = (unsigned)(size_t)xp0;
    const unsigned xp_hi   = (unsigned)((size_t)xp0 >> 32);
    const unsigned yp_lo   = (unsigned)(size_t)yp0;
    const unsigned yp_hi   = (unsigned)((size_t)yp0 >> 32);

    asm volatile(
        // ---------------- prologue ----------------
        "s_mov_b32 m0, -1\n\t"
        "v_mov_b32 v34, %0\n\t"   // Wr/Wo row ptr
        "v_mov_b32 v35, %1\n\t"
        "v_mov_b32 v36, %2\n\t"   // Wi row ptr
        "v_mov_b32 v37, %3\n\t"
        "v_mov_b32 v24, %4\n\t"   // xp
        "v_mov_b32 v25, %5\n\t"
        "v_mov_b32 v26, %6\n\t"   // yp
        "v_mov_b32 v27, %7\n\t"
        "v_mov_b32 v38, %8\n\t"   // bias
        "v_mov_b32 v39, %9\n\t"   // hmask
        "v_mov_b32 v30, %10\n\t"  // lds write addr (w*256+lane*4)
        "v_mov_b32 v31, %11\n\t"  // lds read base  (w*256)
        // weight row -> v40..v89 (50 floats, 200 B)
        "global_load_dwordx4 v[40:43], v[34:35], off\n\t"
        "global_load_dwordx4 v[44:47], v[34:35], off offset:16\n\t"
        "global_load_dwordx4 v[48:51], v[34:35], off offset:32\n\t"
        "global_load_dwordx4 v[52:55], v[34:35], off offset:48\n\t"
        "global_load_dwordx4 v[56:59], v[34:35], off offset:64\n\t"
        "global_load_dwordx4 v[60:63], v[34:35], off offset:80\n\t"
        "global_load_dwordx4 v[64:67], v[34:35], off offset:96\n\t"
        "global_load_dwordx4 v[68:71], v[34:35], off offset:112\n\t"
        "global_load_dwordx4 v[72:75], v[34:35], off offset:128\n\t"
        "global_load_dwordx4 v[76:79], v[34:35], off offset:144\n\t"
        "global_load_dwordx4 v[80:83], v[34:35], off offset:160\n\t"
        "global_load_dwordx4 v[84:87], v[34:35], off offset:176\n\t"
        "global_load_dwordx2 v[88:89], v[34:35], off offset:192\n\t"
        // W_in row -> v90..v97
        "global_load_dwordx4 v[90:93], v[36:37], off\n\t"
        "global_load_dwordx4 v[94:97], v[36:37], off offset:16\n\t"
        // x[0] -> v8..v15
        "global_load_dwordx4 v[8:11], v[24:25], off\n\t"
        "global_load_dwordx4 v[12:15], v[24:25], off offset:16\n\t"
        "s_waitcnt vmcnt(0)\n\t"
        // zero W_in on non-hidden rows (bias already pre-zeroed on host side)
        "v_mul_f32 v90, v39, v90\n\t"
        "v_mul_f32 v91, v39, v91\n\t"
        "v_mul_f32 v92, v39, v92\n\t"
        "v_mul_f32 v93, v39, v93\n\t"
        "v_mul_f32 v94, v39, v94\n\t"
        "v_mul_f32 v95, v39, v95\n\t"
        "v_mul_f32 v96, v39, v96\n\t"
        "v_mul_f32 v97, v39, v97\n\t"
        "v_mov_b32 v28, 0\n\t"        // h = 0
        "s_mov_b32 s66, 0x20000\n\t"  // x step stride (BATCH*INSZ*4)
        "s_movk_i32 s64, 0x1f4\n\t"   // 500 double-iterations
        // ---------------- main loop: 2 steps per iteration ----------------
        "Lt_%=:\n\t"
        "s_sub_u32 s64, s64, 1\n\t"
        // ---- body A (even t): x in v8..15, prefetch -> v16..23 ----
        RELU_PUB
        PRE_A
        RCHAIN
        XFMA_A
        TAIL
        // ---- body B (odd t): x in v16..23, prefetch -> v8..15 ----
        RELU_PUB
        PRE_B
        RCHAIN
        XFMA_B
        TAIL
        "s_cmp_lg_u32 s64, 0\n\t"
        "s_cbranch_scc1 Lt_%=\n\t"
        "s_waitcnt vmcnt(0) lgkmcnt(0)\n\t"
        :
        : "v"(wrow_lo), "v"(wrow_hi),   // %0 %1
          "v"(wip_lo),  "v"(wip_hi),    // %2 %3
          "v"(xp_lo),   "v"(xp_hi),     // %4 %5
          "v"(yp_lo),   "v"(yp_hi),     // %6 %7
          "v"(bias),    "v"(hmask),     // %8 %9
          "v"(ldswr),   "v"(ldsrd),     // %10 %11
          "s"(ymask)                    // %12
        : "memory", "vcc", "scc",
          "s62", "s63", "s64", "s65", "s66",
          "v0","v1","v2","v3","v4","v5","v6","v7",
          "v8","v9","v10","v11","v12","v13","v14","v15",
          "v16","v17","v18","v19","v20","v21","v22","v23",
          "v24","v25","v26","v27","v28","v29","v30","v31",
          "v32","v33","v34","v35","v36","v37","v38","v39",
          "v40","v41","v42","v43","v44","v45","v46","v47",
          "v48","v49","v50","v51","v52","v53","v54","v55",
          "v56","v57","v58","v59","v60","v61","v62","v63",
          "v64","v65","v66","v67","v68","v69","v70","v71",
          "v72","v73","v74","v75","v76","v77","v78","v79",
          "v80","v81","v82","v83","v84","v85","v86","v87",
          "v88","v89","v90","v91","v92","v93","v94","v95",
          "v96","v97"
    );
}

extern "C" void kernel_launch(void* const* d_in, const int* in_sizes, int n_in,
                              void* d_out, int out_size, void* d_ws, size_t ws_size,
                              hipStream_t stream)
{
    const float* xg = (const float*)d_in[0];  // input_seq (1000,4096,8)
    const float* Wi = (const float*)d_in[1];  // W_in (50,8)
    const float* Wr = (const float*)d_in[2];  // W_rec (50,50)
    const float* bs = (const float*)d_in[3];  // bias (50)
    const float* Wo = (const float*)d_in[4];  // W_out_w (6,50)
    const float* bo = (const float*)d_in[5];  // W_out_b (6)
    float* outp = (float*)d_out;              // (1000,4096,6)

    dim3 grid(BATCH / WPB);   // 1024 blocks = 4096 waves = 4/SIMD
    dim3 block(256);
    // 1024 B DYNAMIC LDS: base offset 0 guaranteed, 256 B per wave.
    hipLaunchKernelGGL(biornn_kernel, grid, block, 1024, stream,
                       xg, Wi, Wr, bs, Wo, bo, outp);
}